// Round 11
// baseline (233.557 us; speedup 1.0000x reference)
//
#include <hip/hip_runtime.h>
#include <hip/hip_bf16.h>
#include <math.h>

#define B_   64
#define N_   100
#define K_   16
#define C_   1024
#define R_   8
#define BN_  6400
#define E_   102400
#define MPAD 128   // padded rows per sample

typedef __attribute__((ext_vector_type(8))) short bf16x8;
typedef __attribute__((ext_vector_type(4))) float f32x4;

__device__ __forceinline__ float bf2f(ushort h) {
    union { uint32_t u; float f; } v; v.u = ((uint32_t)h) << 16; return v.f;
}
__device__ __forceinline__ ushort f2bf(float f) {
    union { float f; uint32_t u; } v; v.f = f;
    uint32_t r = v.u + 0x7FFFu + ((v.u >> 16) & 1u);   // RNE
    return (ushort)(r >> 16);
}
__device__ __forceinline__ void gload_lds16(const void* g, void* l) {
    __builtin_amdgcn_global_load_lds(
        (const __attribute__((address_space(1))) void*)g,
        (__attribute__((address_space(3))) void*)l, 16, 0, 0);
}

// ==========================================================================
// PREP mega-kernel: [0,400) edge weights | [400,3600) cast X | [3600,3856) wtrans
// ==========================================================================
__global__ __launch_bounds__(256) void prep_kernel(
        const float* __restrict__ centre, const int* __restrict__ nbr_idx,
        const float* __restrict__ graph_w,
        const float* __restrict__ mr1, const float* __restrict__ mt1,
        const float* __restrict__ pr1, const float* __restrict__ pt1,
        const float* __restrict__ mr2, const float* __restrict__ mt2,
        const float* __restrict__ pr2, const float* __restrict__ pt2,
        const float* __restrict__ X,  const float* __restrict__ CW1,
        const float* __restrict__ CW2,
        float* __restrict__ w1, float* __restrict__ w2,
        ushort* __restrict__ Xb, ushort* __restrict__ Wt1,
        ushort* __restrict__ Wt2) {
    __shared__ ushort T[64][138];
    int bid = blockIdx.x, t = threadIdx.x;
    if (bid < 400) {
        // ---- edge weights; w layout [r][e] ----
        int e = bid * 256 + t;
        int n = e / K_;
        int b = n / N_;
        int fn = b * N_ + nbr_idx[e];
        float dx = centre[2*n]   - centre[2*fn];
        float dy = centre[2*n+1] - centre[2*fn+1];
        float rho   = sqrtf(dx*dx + dy*dy);
        float theta = atan2f(dx, dy);
        const float TWO_PI = 6.28318530717958647692f;
        {
            float w[R_]; float s = 0.f;
            #pragma unroll
            for (int r = 0; r < R_; ++r) {
                float dr = rho - mr1[r];
                float wr = expf(-0.5f * dr * dr / (1e-14f + pr1[r]*pr1[r]));
                float fa = fabsf(theta - mt1[r]);
                float mi = fminf(fa, fabsf(TWO_PI - fa));
                float wt = expf(-0.5f * mi * mi / (1e-14f + pt1[r]*pt1[r]));
                float ww = wr * wt;
                if (isnan(ww)) ww = 0.f;
                w[r] = ww; s += ww;
            }
            float gw = graph_w[e];
            #pragma unroll
            for (int r = 0; r < R_; ++r) w1[(size_t)r * E_ + e] = gw * (w[r] / s);
        }
        {
            float w[R_]; float s = 0.f;
            #pragma unroll
            for (int r = 0; r < R_; ++r) {
                float dr = rho - mr2[r];
                float wr = expf(-0.5f * dr * dr / (1e-14f + pr2[r]*pr2[r]));
                float fa = fabsf(theta - mt2[r]);
                float mi = fminf(fa, fabsf(TWO_PI - fa));
                float wt = expf(-0.5f * mi * mi / (1e-14f + pt2[r]*pt2[r]));
                float ww = wr * wt;
                if (isnan(ww)) ww = 0.f;
                w[r] = ww; s += ww;
            }
            #pragma unroll
            for (int r = 0; r < R_; ++r) w2[(size_t)r * E_ + e] = w[r] / s;
        }
    } else if (bid < 3600) {
        // ---- cast X fp32 -> bf16 into PADDED [64][128][1024] ----
        int gid = (bid - 400) * 256 + t;      // 819200 threads, 8 elems each
        int n  = gid >> 7;                    // node 0..6399
        int c0 = (gid & 127) * 8;
        const float* src = X + (size_t)n * 1024 + c0;
        float4 v0 = *(const float4*)src;
        float4 v1 = *(const float4*)(src + 4);
        bf16x8 o;
        o[0] = (short)f2bf(v0.x); o[1] = (short)f2bf(v0.y);
        o[2] = (short)f2bf(v0.z); o[3] = (short)f2bf(v0.w);
        o[4] = (short)f2bf(v1.x); o[5] = (short)f2bf(v1.y);
        o[6] = (short)f2bf(v1.z); o[7] = (short)f2bf(v1.w);
        int prow = (n / 100) * MPAD + (n % 100);
        *(bf16x8*)&Xb[(size_t)prow * 1024 + c0] = o;
    } else {
        // ---- weight transpose: conv_w -> Wt[j][c] bf16 ----
        int w = bid - 3600;                   // 256 = 16ct x 8r x 2layer
        int layer = w >> 7, rr = (w >> 4) & 7, ct = w & 15;
        const float* W = layer ? CW2 : CW1;
        ushort*    Wt = layer ? Wt2 : Wt1;
        int c0 = ct * 64;
        int lane6 = t & 63;
        #pragma unroll
        for (int it = 0; it < 16; ++it) {
            int ch = (t >> 6) + 4 * it;
            int d  = lane6 * 2;
            float2 v = *(const float2*)&W[(((size_t)rr << 10) + c0 + ch) * 128 + d];
            T[ch][d]     = f2bf(v.x);
            T[ch][d + 1] = f2bf(v.y);
        }
        __syncthreads();
        #pragma unroll
        for (int it = 0; it < 32; ++it) {
            int d = (t >> 6) + 4 * it;
            Wt[(size_t)(rr * 128 + d) * 1024 + c0 + lane6] = T[lane6][d];
        }
    }
}

// ==========================================================================
// Fused GEMM+aggregate v2.  grid 1024 = 64 samples x 16 colblocks(64).
// M=128 (padded), N=64, BK=32, 4 waves (2Mx2N), 64x32 wave tiles, dbuf,
// LDS union (main-loop A/B <-> epilogue P/w/f) = 25.6 KB -> 4 wg/CU.
// ==========================================================================
union SharedU {
    struct { ushort A[2][128][32]; ushort Bm[2][64][32]; } m;   // 24.6 KB
    struct { ushort P[100][64]; float w[1600]; int f[1600]; } e; // 25.6 KB
};

__global__ __launch_bounds__(256) void fused_gemm_agg_kernel(
        const ushort* __restrict__ Xb,    // [64*128][1024] padded bf16
        const ushort* __restrict__ Wt,    // [1024][1024] bf16
        const float* __restrict__ wR,     // [R][E]
        const int*   __restrict__ nbr,    // [BN][16]
        ushort* __restrict__ outB,        // padded bf16 h (layer 1) or null
        float*  __restrict__ outF) {      // fp32 out (layer 2) or null
    __shared__ SharedU su;
    int bid = blockIdx.x;                       // 1024 = 8 XCDs * 128
    int swz = (bid & 7) * 128 + (bid >> 3);     // bijective; 16 consecutive = same sample
    int sample = swz >> 4, cb = swz & 15;
    int t = threadIdx.x, wid = t >> 6, lane = t & 63;
    int wm = wid >> 1, wn = wid & 1;

    int srow  = lane >> 2;
    int sslot = (lane & 3) ^ ((lane >> 2) & 3) ^ (lane >> 4);
    int pslot = (lane >> 4) ^ (lane & 3) ^ ((lane >> 2) & 3);

    const ushort* agp = Xb + (size_t)(sample * MPAD + srow) * 1024 + sslot * 8;
    const ushort* bgp = Wt + (size_t)(cb * 64 + srow) * 1024 + sslot * 8;

    f32x4 acc[4][2];
    #pragma unroll
    for (int i = 0; i < 4; ++i) { acc[i][0] = (f32x4)0.f; acc[i][1] = (f32x4)0.f; }

    // prologue: stage K-step 0 into buf 0 (A blocks wid, wid+4; B block wid)
    gload_lds16(agp + (size_t)(wid * 16) * 1024,       &su.m.A[0][wid * 16][0]);
    gload_lds16(agp + (size_t)((wid + 4) * 16) * 1024, &su.m.A[0][(wid + 4) * 16][0]);
    gload_lds16(bgp + (size_t)(wid * 16) * 1024,       &su.m.Bm[0][wid * 16][0]);
    __syncthreads();

    for (int ts = 0; ts < 32; ++ts) {
        int cur = ts & 1;
        if (ts < 31) {
            int c1 = (ts + 1) * 32;
            gload_lds16(agp + (size_t)(wid * 16) * 1024 + c1,       &su.m.A[cur ^ 1][wid * 16][0]);
            gload_lds16(agp + (size_t)((wid + 4) * 16) * 1024 + c1, &su.m.A[cur ^ 1][(wid + 4) * 16][0]);
            gload_lds16(bgp + (size_t)(wid * 16) * 1024 + c1,       &su.m.Bm[cur ^ 1][wid * 16][0]);
        }
        bf16x8 af[4], bfr[2];
        #pragma unroll
        for (int mi = 0; mi < 4; ++mi)
            af[mi] = *(const bf16x8*)&su.m.A[cur][wm * 64 + mi * 16 + (lane & 15)][pslot * 8];
        #pragma unroll
        for (int ni = 0; ni < 2; ++ni)
            bfr[ni] = *(const bf16x8*)&su.m.Bm[cur][wn * 32 + ni * 16 + (lane & 15)][pslot * 8];
        #pragma unroll
        for (int mi = 0; mi < 4; ++mi)
            #pragma unroll
            for (int ni = 0; ni < 2; ++ni)
                acc[mi][ni] = __builtin_amdgcn_mfma_f32_16x16x32_bf16(
                    af[mi], bfr[ni], acc[mi][ni], 0, 0, 0);
        __syncthreads();
    }

    // ---- epilogue 1: acc -> P_lds (row<100 guard), XOR swizzle col^(((row>>2)&3)<<4)
    #pragma unroll
    for (int mi = 0; mi < 4; ++mi) {
        #pragma unroll
        for (int ni = 0; ni < 2; ++ni) {
            int col = wn * 32 + ni * 16 + (lane & 15);
            #pragma unroll
            for (int q = 0; q < 4; ++q) {
                int row = wm * 64 + mi * 16 + (lane >> 4) * 4 + q;
                if (row < 100)
                    su.e.P[row][col ^ (((row >> 2) & 3) << 4)] = f2bf(acc[mi][ni][q]);
            }
        }
    }
    // ---- epilogue 2: w-slice (r = cb>>1) + neighbor ids
    {
        const float* wsrc = wR + (size_t)(cb >> 1) * E_ + (size_t)sample * 1600;
        const int*   nsrc = nbr + (size_t)sample * 1600;
        #pragma unroll
        for (int q = 0; q < 7; ++q) {   // 7*256 = 1792 >= 1600
            int i = t + q * 256;
            if (i < 1600) { su.e.w[i] = wsrc[i]; su.e.f[i] = nsrc[i]; }
        }
    }
    __syncthreads();

    // ---- epilogue 3: aggregate.  thread: col-pair cp=t&31, node-group ng=t>>5
    int cp = t & 31, ng = t >> 5;
    int j0 = cp * 2;
    for (int i = 0; i < 13; ++i) {
        int n = ng + 8 * i;
        if (n >= 100) break;
        float a0 = 0.f, a1 = 0.f;
        #pragma unroll
        for (int k = 0; k < 16; ++k) {
            int row  = su.e.f[n * 16 + k];
            float wk = su.e.w[n * 16 + k];
            ushort2 v = *(const ushort2*)&su.e.P[row][j0 ^ (((row >> 2) & 3) << 4)];
            a0 += wk * bf2f(v.x);
            a1 += wk * bf2f(v.y);
        }
        a0 = fmaxf(a0, 0.f);
        a1 = fmaxf(a1, 0.f);
        if (outB) {
            ushort2 o; o.x = f2bf(a0); o.y = f2bf(a1);
            *(ushort2*)&outB[(size_t)(sample * MPAD + n) * 1024 + cb * 64 + j0] = o;
        } else {
            float2 o; o.x = a0; o.y = a1;
            *(float2*)&outF[(size_t)(sample * 100 + n) * 1024 + cb * 64 + j0] = o;
        }
    }
}

// ==========================================================================
extern "C" void kernel_launch(void* const* d_in, const int* in_sizes, int n_in,
                              void* d_out, int out_size, void* d_ws, size_t ws_size,
                              hipStream_t stream) {
    const float* node_feats = (const float*)d_in[0];
    const float* centre     = (const float*)d_in[1];
    const float* graph_w    = (const float*)d_in[2];
    const int*   nbr_idx    = (const int*)  d_in[3];
    const float* mr1 = (const float*)d_in[4];
    const float* mt1 = (const float*)d_in[5];
    const float* pr1 = (const float*)d_in[6];
    const float* pt1 = (const float*)d_in[7];
    const float* cw1 = (const float*)d_in[8];
    const float* mr2 = (const float*)d_in[9];
    const float* mt2 = (const float*)d_in[10];
    const float* pr2 = (const float*)d_in[11];
    const float* pt2 = (const float*)d_in[12];
    const float* cw2 = (const float*)d_in[13];

    char* ws = (char*)d_ws;
    ushort* Xb  = (ushort*)ws;  ws += (size_t)B_ * MPAD * 1024 * 2;  // 16.8 MB (padded)
    ushort* hb  = (ushort*)ws;  ws += (size_t)B_ * MPAD * 1024 * 2;  // 16.8 MB (padded)
    ushort* W1t = (ushort*)ws;  ws += (size_t)1024 * 1024 * 2;       // 2 MB
    ushort* W2t = (ushort*)ws;  ws += (size_t)1024 * 1024 * 2;       // 2 MB
    float*  w1  = (float*)ws;   ws += (size_t)R_ * E_ * 4;           // 3.28 MB
    float*  w2  = (float*)ws;                                        // 3.28 MB

    float* out = (float*)d_out;

    prep_kernel<<<3856, 256, 0, stream>>>(
        centre, nbr_idx, graph_w, mr1, mt1, pr1, pt1, mr2, mt2, pr2, pt2,
        node_feats, cw1, cw2, w1, w2, Xb, W1t, W2t);

    fused_gemm_agg_kernel<<<1024, 256, 0, stream>>>(Xb, W1t, w1, nbr_idx, hb, nullptr);
    fused_gemm_agg_kernel<<<1024, 256, 0, stream>>>(hb, W2t, w2, nbr_idx, nullptr, out);
}

// Round 12
// 221.639 us; speedup vs baseline: 1.0538x; 1.0538x over previous
//
#include <hip/hip_runtime.h>
#include <hip/hip_bf16.h>
#include <math.h>

#define B_   64
#define N_   100
#define K_   16
#define C_   1024
#define R_   8
#define BN_  6400
#define E_   102400

typedef __attribute__((ext_vector_type(8))) short bf16x8;
typedef __attribute__((ext_vector_type(4))) float f32x4;

__device__ __forceinline__ float bf2f(ushort h) {
    union { uint32_t u; float f; } v; v.u = ((uint32_t)h) << 16; return v.f;
}
__device__ __forceinline__ ushort f2bf(float f) {
    union { float f; uint32_t u; } v; v.f = f;
    uint32_t r = v.u + 0x7FFFu + ((v.u >> 16) & 1u);   // RNE
    return (ushort)(r >> 16);
}
__device__ __forceinline__ void gload_lds16(const void* g, void* l) {
    __builtin_amdgcn_global_load_lds(
        (const __attribute__((address_space(1))) void*)g,
        (__attribute__((address_space(3))) void*)l, 16, 0, 0);
}

// ==========================================================================
// PREP mega-kernel: [0,400) edge weights | [400,3600) cast X | [3600,3856) wtrans
// ==========================================================================
__global__ __launch_bounds__(256) void prep_kernel(
        const float* __restrict__ centre, const int* __restrict__ nbr_idx,
        const float* __restrict__ graph_w,
        const float* __restrict__ mr1, const float* __restrict__ mt1,
        const float* __restrict__ pr1, const float* __restrict__ pt1,
        const float* __restrict__ mr2, const float* __restrict__ mt2,
        const float* __restrict__ pr2, const float* __restrict__ pt2,
        const float* __restrict__ X,  const float* __restrict__ CW1,
        const float* __restrict__ CW2,
        float* __restrict__ w1, float* __restrict__ w2,
        ushort* __restrict__ Xb, ushort* __restrict__ Wt1,
        ushort* __restrict__ Wt2) {
    __shared__ ushort T[64][138];
    int bid = blockIdx.x, t = threadIdx.x;
    if (bid < 400) {
        // ---- edge weights; w layout [r][e] ----
        int e = bid * 256 + t;
        int n = e / K_;
        int b = n / N_;
        int fn = b * N_ + nbr_idx[e];
        float dx = centre[2*n]   - centre[2*fn];
        float dy = centre[2*n+1] - centre[2*fn+1];
        float rho   = sqrtf(dx*dx + dy*dy);
        float theta = atan2f(dx, dy);
        const float TWO_PI = 6.28318530717958647692f;
        {
            float w[R_]; float s = 0.f;
            #pragma unroll
            for (int r = 0; r < R_; ++r) {
                float dr = rho - mr1[r];
                float wr = expf(-0.5f * dr * dr / (1e-14f + pr1[r]*pr1[r]));
                float fa = fabsf(theta - mt1[r]);
                float mi = fminf(fa, fabsf(TWO_PI - fa));
                float wt = expf(-0.5f * mi * mi / (1e-14f + pt1[r]*pt1[r]));
                float ww = wr * wt;
                if (isnan(ww)) ww = 0.f;
                w[r] = ww; s += ww;
            }
            float gw = graph_w[e];
            #pragma unroll
            for (int r = 0; r < R_; ++r) w1[(size_t)r * E_ + e] = gw * (w[r] / s);
        }
        {
            float w[R_]; float s = 0.f;
            #pragma unroll
            for (int r = 0; r < R_; ++r) {
                float dr = rho - mr2[r];
                float wr = expf(-0.5f * dr * dr / (1e-14f + pr2[r]*pr2[r]));
                float fa = fabsf(theta - mt2[r]);
                float mi = fminf(fa, fabsf(TWO_PI - fa));
                float wt = expf(-0.5f * mi * mi / (1e-14f + pt2[r]*pt2[r]));
                float ww = wr * wt;
                if (isnan(ww)) ww = 0.f;
                w[r] = ww; s += ww;
            }
            #pragma unroll
            for (int r = 0; r < R_; ++r) w2[(size_t)r * E_ + e] = w[r] / s;
        }
    } else if (bid < 3600) {
        // ---- cast X fp32 -> bf16, unpadded [6400][1024] ----
        int gid = (bid - 400) * 256 + t;
        int n  = gid >> 7;
        int c0 = (gid & 127) * 8;
        const float* src = X + (size_t)n * 1024 + c0;
        float4 v0 = *(const float4*)src;
        float4 v1 = *(const float4*)(src + 4);
        bf16x8 o;
        o[0] = (short)f2bf(v0.x); o[1] = (short)f2bf(v0.y);
        o[2] = (short)f2bf(v0.z); o[3] = (short)f2bf(v0.w);
        o[4] = (short)f2bf(v1.x); o[5] = (short)f2bf(v1.y);
        o[6] = (short)f2bf(v1.z); o[7] = (short)f2bf(v1.w);
        *(bf16x8*)&Xb[(size_t)n * 1024 + c0] = o;
    } else {
        // ---- weight transpose: conv_w -> Wt[j][c] bf16 ----
        int w = bid - 3600;                   // 256 = 16ct x 8r x 2layer
        int layer = w >> 7, rr = (w >> 4) & 7, ct = w & 15;
        const float* W = layer ? CW2 : CW1;
        ushort*    Wt = layer ? Wt2 : Wt1;
        int c0 = ct * 64;
        int lane6 = t & 63;
        #pragma unroll
        for (int it = 0; it < 16; ++it) {
            int ch = (t >> 6) + 4 * it;
            int d  = lane6 * 2;
            float2 v = *(const float2*)&W[(((size_t)rr << 10) + c0 + ch) * 128 + d];
            T[ch][d]     = f2bf(v.x);
            T[ch][d + 1] = f2bf(v.y);
        }
        __syncthreads();
        #pragma unroll
        for (int it = 0; it < 32; ++it) {
            int d = (t >> 6) + 4 * it;
            Wt[(size_t)(rr * 128 + d) * 1024 + c0 + lane6] = T[lane6][d];
        }
    }
}

// ==========================================================================
// Fused GEMM+aggregate — R7 geometry + LDS union (the single change).
// One wg = (sample, colblock cb of 128): P tile 100x128 via MFMA (M pad 112),
// then in-LDS aggregate.  grid 512 = 64 x 8.  BK=32, dbuf.
// LDS = union(main 30.7 KB, epi 38.4 KB) = 38.4 KB -> 4 wg/CU (was 69 KB/2).
// ==========================================================================
union SharedU {
    struct { ushort A[2][112][32]; ushort Bm[2][128][32]; } m;   // 30720 B
    struct { ushort P[100][128]; float w[1600]; int f[1600]; } e; // 38400 B
};

__global__ __launch_bounds__(256) void fused_gemm_agg_kernel(
        const ushort* __restrict__ Xb,    // [6400][1024] bf16 (layer input)
        const ushort* __restrict__ Wt,    // [1024][1024] bf16
        const float* __restrict__ wR,     // [R][E] edge weights
        const int*   __restrict__ nbr,    // [BN][16]
        ushort* __restrict__ outB,        // bf16 h   (layer 1) or null
        float*  __restrict__ outF) {      // fp32 out (layer 2) or null
    __shared__ SharedU su;
    int bid = blockIdx.x;                       // 512 = 8 XCDs * 64
    int swz = (bid & 7) * 64 + (bid >> 3);      // bijective
    int sample = swz >> 3, cb = swz & 7;
    int t = threadIdx.x, wid = t >> 6, lane = t & 63;

    int srow  = lane >> 2;
    int sslot = (lane & 3) ^ ((lane >> 2) & 3) ^ (lane >> 4);
    int pslot = (lane >> 4) ^ (lane & 3) ^ ((lane >> 2) & 3);

    const ushort* agp = Xb + (size_t)(sample * 100 + srow) * 1024 + sslot * 8;
    const ushort* bgp = Wt + (size_t)(cb * 128 + srow) * 1024 + sslot * 8;

    f32x4 acc[7][2];
    #pragma unroll
    for (int i = 0; i < 7; ++i) { acc[i][0] = (f32x4)0.f; acc[i][1] = (f32x4)0.f; }

    // prologue: stage K-step 0 into buf 0
    #pragma unroll
    for (int q = 0; q < 2; ++q) {
        int ch = wid + 4 * q;
        if (ch < 7) gload_lds16(agp + (size_t)ch * 16 * 1024, &su.m.A[0][ch * 16][0]);
        gload_lds16(bgp + (size_t)ch * 16 * 1024, &su.m.Bm[0][ch * 16][0]);
    }
    __syncthreads();

    for (int ts = 0; ts < 32; ++ts) {
        int cur = ts & 1;
        if (ts < 31) {
            int c1 = (ts + 1) * 32;
            #pragma unroll
            for (int q = 0; q < 2; ++q) {
                int ch = wid + 4 * q;
                if (ch < 7) gload_lds16(agp + (size_t)ch * 16 * 1024 + c1,
                                        &su.m.A[cur ^ 1][ch * 16][0]);
                gload_lds16(bgp + (size_t)ch * 16 * 1024 + c1,
                            &su.m.Bm[cur ^ 1][ch * 16][0]);
            }
        }
        bf16x8 af[7], bfr[2];
        #pragma unroll
        for (int mi = 0; mi < 7; ++mi)
            af[mi] = *(const bf16x8*)&su.m.A[cur][mi * 16 + (lane & 15)][pslot * 8];
        #pragma unroll
        for (int ni = 0; ni < 2; ++ni)
            bfr[ni] = *(const bf16x8*)&su.m.Bm[cur][wid * 32 + ni * 16 + (lane & 15)][pslot * 8];
        #pragma unroll
        for (int mi = 0; mi < 7; ++mi)
            #pragma unroll
            for (int ni = 0; ni < 2; ++ni)
                acc[mi][ni] = __builtin_amdgcn_mfma_f32_16x16x32_bf16(
                    af[mi], bfr[ni], acc[mi][ni], 0, 0, 0);
        __syncthreads();
    }

    // ---- epilogue 1: acc -> P_lds (row<100 guard), XOR swizzle col^(((row>>2)&3)<<4)
    #pragma unroll
    for (int mi = 0; mi < 7; ++mi) {
        #pragma unroll
        for (int ni = 0; ni < 2; ++ni) {
            int colb = wid * 32 + ni * 16 + (lane & 15);
            #pragma unroll
            for (int q = 0; q < 4; ++q) {
                int row = mi * 16 + (lane >> 4) * 4 + q;
                if (row < 100)
                    su.e.P[row][colb ^ (((row >> 2) & 3) << 4)] = f2bf(acc[mi][ni][q]);
            }
        }
    }
    // ---- epilogue 2: w-slice (r = cb) + neighbor ids for this sample
    {
        const float* wsrc = wR + (size_t)cb * E_ + (size_t)sample * 1600;
        const int*   nsrc = nbr + (size_t)sample * 1600;
        #pragma unroll
        for (int q = 0; q < 7; ++q) {   // 7*256 = 1792 >= 1600
            int i = t + q * 256;
            if (i < 1600) { su.e.w[i] = wsrc[i]; su.e.f[i] = nsrc[i]; }
        }
    }
    __syncthreads();

    // ---- epilogue 3: aggregate.  thread: j-pair p = lane, node n = wid + 4i
    int p = lane;                // j = 2p, 2p+1
    int nb = wid;
    for (int i = 0; i < 25; ++i) {
        int n = nb + 4 * i;
        float a0 = 0.f, a1 = 0.f;
        #pragma unroll
        for (int k = 0; k < 16; ++k) {
            int row  = su.e.f[n * 16 + k];
            float wk = su.e.w[n * 16 + k];
            ushort2 v = *(const ushort2*)&su.e.P[row][(2 * p) ^ (((row >> 2) & 3) << 4)];
            a0 += wk * bf2f(v.x);
            a1 += wk * bf2f(v.y);
        }
        a0 = fmaxf(a0, 0.f);
        a1 = fmaxf(a1, 0.f);
        size_t base = (size_t)(sample * 100 + n) * 1024 + cb * 128 + 2 * p;
        if (outB) {
            ushort2 o; o.x = f2bf(a0); o.y = f2bf(a1);
            *(ushort2*)&outB[base] = o;
        } else {
            float2 o; o.x = a0; o.y = a1;
            *(float2*)&outF[base] = o;
        }
    }
}

// ==========================================================================
extern "C" void kernel_launch(void* const* d_in, const int* in_sizes, int n_in,
                              void* d_out, int out_size, void* d_ws, size_t ws_size,
                              hipStream_t stream) {
    const float* node_feats = (const float*)d_in[0];
    const float* centre     = (const float*)d_in[1];
    const float* graph_w    = (const float*)d_in[2];
    const int*   nbr_idx    = (const int*)  d_in[3];
    const float* mr1 = (const float*)d_in[4];
    const float* mt1 = (const float*)d_in[5];
    const float* pr1 = (const float*)d_in[6];
    const float* pt1 = (const float*)d_in[7];
    const float* cw1 = (const float*)d_in[8];
    const float* mr2 = (const float*)d_in[9];
    const float* mt2 = (const float*)d_in[10];
    const float* pr2 = (const float*)d_in[11];
    const float* pt2 = (const float*)d_in[12];
    const float* cw2 = (const float*)d_in[13];

    char* ws = (char*)d_ws;
    ushort* Xb  = (ushort*)ws;  ws += (size_t)BN_ * 1024 * 2;   // 13.1 MB
    ushort* hb  = (ushort*)ws;  ws += (size_t)BN_ * 1024 * 2;   // 13.1 MB
    ushort* W1t = (ushort*)ws;  ws += (size_t)1024 * 1024 * 2;  // 2 MB
    ushort* W2t = (ushort*)ws;  ws += (size_t)1024 * 1024 * 2;  // 2 MB
    float*  w1  = (float*)ws;   ws += (size_t)R_ * E_ * 4;      // 3.28 MB
    float*  w2  = (float*)ws;                                   // 3.28 MB

    float* out = (float*)d_out;

    prep_kernel<<<3856, 256, 0, stream>>>(
        centre, nbr_idx, graph_w, mr1, mt1, pr1, pt1, mr2, mt2, pr2, pt2,
        node_feats, cw1, cw2, w1, w2, Xb, W1t, W2t);

    fused_gemm_agg_kernel<<<512, 256, 0, stream>>>(Xb, W1t, w1, nbr_idx, hb, nullptr);
    fused_gemm_agg_kernel<<<512, 256, 0, stream>>>(hb, W2t, w2, nbr_idx, nullptr, out);
}

// Round 13
// 183.537 us; speedup vs baseline: 1.2725x; 1.2076x over previous
//
#include <hip/hip_runtime.h>
#include <hip/hip_bf16.h>
#include <math.h>

#define B_   64
#define N_   100
#define K_   16
#define C_   1024
#define R_   8
#define BN_  6400
#define E_   102400

typedef __attribute__((ext_vector_type(8))) short bf16x8;
typedef __attribute__((ext_vector_type(4))) float f32x4;

__device__ __forceinline__ float bf2f(ushort h) {
    union { uint32_t u; float f; } v; v.u = ((uint32_t)h) << 16; return v.f;
}
__device__ __forceinline__ ushort f2bf(float f) {
    union { float f; uint32_t u; } v; v.f = f;
    uint32_t r = v.u + 0x7FFFu + ((v.u >> 16) & 1u);   // RNE
    return (ushort)(r >> 16);
}
__device__ __forceinline__ void gload_lds16(const void* g, void* l) {
    __builtin_amdgcn_global_load_lds(
        (const __attribute__((address_space(1))) void*)g,
        (__attribute__((address_space(3))) void*)l, 16, 0, 0);
}

// ==========================================================================
// PREP mega-kernel: [0,400) edge weights | [400,3600) cast X | [3600,3856) wtrans
// (validated in R11/R12 — unchanged)
// ==========================================================================
__global__ __launch_bounds__(256) void prep_kernel(
        const float* __restrict__ centre, const int* __restrict__ nbr_idx,
        const float* __restrict__ graph_w,
        const float* __restrict__ mr1, const float* __restrict__ mt1,
        const float* __restrict__ pr1, const float* __restrict__ pt1,
        const float* __restrict__ mr2, const float* __restrict__ mt2,
        const float* __restrict__ pr2, const float* __restrict__ pt2,
        const float* __restrict__ X,  const float* __restrict__ CW1,
        const float* __restrict__ CW2,
        float* __restrict__ w1, float* __restrict__ w2,
        ushort* __restrict__ Xb, ushort* __restrict__ Wt1,
        ushort* __restrict__ Wt2) {
    __shared__ ushort T[64][138];
    int bid = blockIdx.x, t = threadIdx.x;
    if (bid < 400) {
        int e = bid * 256 + t;
        int n = e / K_;
        int b = n / N_;
        int fn = b * N_ + nbr_idx[e];
        float dx = centre[2*n]   - centre[2*fn];
        float dy = centre[2*n+1] - centre[2*fn+1];
        float rho   = sqrtf(dx*dx + dy*dy);
        float theta = atan2f(dx, dy);
        const float TWO_PI = 6.28318530717958647692f;
        {
            float w[R_]; float s = 0.f;
            #pragma unroll
            for (int r = 0; r < R_; ++r) {
                float dr = rho - mr1[r];
                float wr = expf(-0.5f * dr * dr / (1e-14f + pr1[r]*pr1[r]));
                float fa = fabsf(theta - mt1[r]);
                float mi = fminf(fa, fabsf(TWO_PI - fa));
                float wt = expf(-0.5f * mi * mi / (1e-14f + pt1[r]*pt1[r]));
                float ww = wr * wt;
                if (isnan(ww)) ww = 0.f;
                w[r] = ww; s += ww;
            }
            float gw = graph_w[e];
            #pragma unroll
            for (int r = 0; r < R_; ++r) w1[(size_t)r * E_ + e] = gw * (w[r] / s);
        }
        {
            float w[R_]; float s = 0.f;
            #pragma unroll
            for (int r = 0; r < R_; ++r) {
                float dr = rho - mr2[r];
                float wr = expf(-0.5f * dr * dr / (1e-14f + pr2[r]*pr2[r]));
                float fa = fabsf(theta - mt2[r]);
                float mi = fminf(fa, fabsf(TWO_PI - fa));
                float wt = expf(-0.5f * mi * mi / (1e-14f + pt2[r]*pt2[r]));
                float ww = wr * wt;
                if (isnan(ww)) ww = 0.f;
                w[r] = ww; s += ww;
            }
            #pragma unroll
            for (int r = 0; r < R_; ++r) w2[(size_t)r * E_ + e] = w[r] / s;
        }
    } else if (bid < 3600) {
        int gid = (bid - 400) * 256 + t;
        int n  = gid >> 7;
        int c0 = (gid & 127) * 8;
        const float* src = X + (size_t)n * 1024 + c0;
        float4 v0 = *(const float4*)src;
        float4 v1 = *(const float4*)(src + 4);
        bf16x8 o;
        o[0] = (short)f2bf(v0.x); o[1] = (short)f2bf(v0.y);
        o[2] = (short)f2bf(v0.z); o[3] = (short)f2bf(v0.w);
        o[4] = (short)f2bf(v1.x); o[5] = (short)f2bf(v1.y);
        o[6] = (short)f2bf(v1.z); o[7] = (short)f2bf(v1.w);
        *(bf16x8*)&Xb[(size_t)n * 1024 + c0] = o;
    } else {
        int w = bid - 3600;
        int layer = w >> 7, rr = (w >> 4) & 7, ct = w & 15;
        const float* W = layer ? CW2 : CW1;
        ushort*    Wt = layer ? Wt2 : Wt1;
        int c0 = ct * 64;
        int lane6 = t & 63;
        #pragma unroll
        for (int it = 0; it < 16; ++it) {
            int ch = (t >> 6) + 4 * it;
            int d  = lane6 * 2;
            float2 v = *(const float2*)&W[(((size_t)rr << 10) + c0 + ch) * 128 + d];
            T[ch][d]     = f2bf(v.x);
            T[ch][d + 1] = f2bf(v.y);
        }
        __syncthreads();
        #pragma unroll
        for (int it = 0; it < 32; ++it) {
            int d = (t >> 6) + 4 * it;
            Wt[(size_t)(rr * 128 + d) * 1024 + c0 + lane6] = T[lane6][d];
        }
    }
}

// ==========================================================================
// Fused GEMM+aggregate v4: 8 waves (512 thr), 128x128 tile, SEPARATE LDS
// arrays (union proved toxic: R11/R12 conflict 6-8x).  grid 512 = 64 x 8
// = 2 wg/CU, 16 waves/CU (4/SIMD).  BK=32, dbuf.  LDS 71168 B.
// Wave grid 2M x 4N: per wave af[4] x bfr[2] = 8 MFMA : 6 ds_read_b128.
// A rows 100..127 over-stage into adjacent valid ws memory (row-guarded out).
// ==========================================================================
__global__ __launch_bounds__(512, 4) void fused_gemm_agg_kernel(
        const ushort* __restrict__ Xb,    // [6400][1024] bf16 (layer input)
        const ushort* __restrict__ Wt,    // [1024][1024] bf16
        const float* __restrict__ wR,     // [R][E] edge weights
        const int*   __restrict__ nbr,    // [BN][16]
        ushort* __restrict__ outB,        // bf16 h   (layer 1) or null
        float*  __restrict__ outF) {      // fp32 out (layer 2) or null
    __shared__ ushort As[2][128][32];
    __shared__ ushort Bs[2][128][32];
    __shared__ ushort P_lds[100][128];
    __shared__ float  w_lds[1600];
    __shared__ int    f_lds[1600];

    int bid = blockIdx.x;                       // 512 = 8 XCDs * 64
    int swz = (bid & 7) * 64 + (bid >> 3);      // bijective; same-XCD shares sample
    int sample = swz >> 3, cb = swz & 7;
    int t = threadIdx.x, wid = t >> 6, lane = t & 63;
    int wm = wid >> 2, wn = wid & 3;

    int srow  = lane >> 2;
    int sslot = (lane & 3) ^ ((lane >> 2) & 3) ^ (lane >> 4);
    int pslot = (lane >> 4) ^ (lane & 3) ^ ((lane >> 2) & 3);

    const ushort* agp = Xb + (size_t)(sample * 100 + wid * 16 + srow) * 1024 + sslot * 8;
    const ushort* bgp = Wt + (size_t)(cb * 128 + wid * 16 + srow) * 1024 + sslot * 8;

    f32x4 acc[4][2];
    #pragma unroll
    for (int i = 0; i < 4; ++i) { acc[i][0] = (f32x4)0.f; acc[i][1] = (f32x4)0.f; }

    // prologue: stage K-step 0 into buf 0 (each wave: 16 A rows + 16 B rows)
    gload_lds16(agp, &As[0][wid * 16][0]);
    gload_lds16(bgp, &Bs[0][wid * 16][0]);
    __syncthreads();

    for (int ts = 0; ts < 32; ++ts) {
        int cur = ts & 1;
        if (ts < 31) {
            int c1 = (ts + 1) * 32;
            gload_lds16(agp + c1, &As[cur ^ 1][wid * 16][0]);
            gload_lds16(bgp + c1, &Bs[cur ^ 1][wid * 16][0]);
        }
        bf16x8 af[4], bfr[2];
        #pragma unroll
        for (int mi = 0; mi < 4; ++mi)
            af[mi] = *(const bf16x8*)&As[cur][wm * 64 + mi * 16 + (lane & 15)][pslot * 8];
        #pragma unroll
        for (int ni = 0; ni < 2; ++ni)
            bfr[ni] = *(const bf16x8*)&Bs[cur][wn * 32 + ni * 16 + (lane & 15)][pslot * 8];
        #pragma unroll
        for (int mi = 0; mi < 4; ++mi)
            #pragma unroll
            for (int ni = 0; ni < 2; ++ni)
                acc[mi][ni] = __builtin_amdgcn_mfma_f32_16x16x32_bf16(
                    af[mi], bfr[ni], acc[mi][ni], 0, 0, 0);
        __syncthreads();
    }

    // ---- epilogue 1: acc -> P_lds (row<100 guard), XOR swizzle col^(((row>>2)&3)<<4)
    #pragma unroll
    for (int mi = 0; mi < 4; ++mi) {
        #pragma unroll
        for (int ni = 0; ni < 2; ++ni) {
            int col = wn * 32 + ni * 16 + (lane & 15);
            #pragma unroll
            for (int q = 0; q < 4; ++q) {
                int row = wm * 64 + mi * 16 + (lane >> 4) * 4 + q;
                if (row < 100)
                    P_lds[row][col ^ (((row >> 2) & 3) << 4)] = f2bf(acc[mi][ni][q]);
            }
        }
    }
    // ---- epilogue 2: w-slice (r = cb) + neighbor ids for this sample
    {
        const float* wsrc = wR + (size_t)cb * E_ + (size_t)sample * 1600;
        const int*   nsrc = nbr + (size_t)sample * 1600;
        #pragma unroll
        for (int q = 0; q < 4; ++q) {   // 4*512 = 2048 >= 1600
            int i = t + q * 512;
            if (i < 1600) { w_lds[i] = wsrc[i]; f_lds[i] = nsrc[i]; }
        }
    }
    __syncthreads();

    // ---- epilogue 3: aggregate.  thread: j-pair p = lane, node n = wid + 8i
    int p = lane;                // j = 2p, 2p+1
    for (int i = 0; i < 13; ++i) {
        int n = wid + 8 * i;
        if (n >= 100) break;
        float a0 = 0.f, a1 = 0.f;
        #pragma unroll
        for (int k = 0; k < 16; ++k) {
            int row  = f_lds[n * 16 + k];
            float wk = w_lds[n * 16 + k];
            ushort2 v = *(const ushort2*)&P_lds[row][(2 * p) ^ (((row >> 2) & 3) << 4)];
            a0 += wk * bf2f(v.x);
            a1 += wk * bf2f(v.y);
        }
        a0 = fmaxf(a0, 0.f);
        a1 = fmaxf(a1, 0.f);
        size_t base = (size_t)(sample * 100 + n) * 1024 + cb * 128 + 2 * p;
        if (outB) {
            ushort2 o; o.x = f2bf(a0); o.y = f2bf(a1);
            *(ushort2*)&outB[base] = o;
        } else {
            float2 o; o.x = a0; o.y = a1;
            *(float2*)&outF[base] = o;
        }
    }
}

// ==========================================================================
extern "C" void kernel_launch(void* const* d_in, const int* in_sizes, int n_in,
                              void* d_out, int out_size, void* d_ws, size_t ws_size,
                              hipStream_t stream) {
    const float* node_feats = (const float*)d_in[0];
    const float* centre     = (const float*)d_in[1];
    const float* graph_w    = (const float*)d_in[2];
    const int*   nbr_idx    = (const int*)  d_in[3];
    const float* mr1 = (const float*)d_in[4];
    const float* mt1 = (const float*)d_in[5];
    const float* pr1 = (const float*)d_in[6];
    const float* pt1 = (const float*)d_in[7];
    const float* cw1 = (const float*)d_in[8];
    const float* mr2 = (const float*)d_in[9];
    const float* mt2 = (const float*)d_in[10];
    const float* pr2 = (const float*)d_in[11];
    const float* pt2 = (const float*)d_in[12];
    const float* cw2 = (const float*)d_in[13];

    char* ws = (char*)d_ws;
    ushort* Xb  = (ushort*)ws;  ws += (size_t)BN_ * 1024 * 2;   // 13.1 MB
    ushort* hb  = (ushort*)ws;  ws += (size_t)BN_ * 1024 * 2;   // 13.1 MB
    ushort* W1t = (ushort*)ws;  ws += (size_t)1024 * 1024 * 2;  // 2 MB
    ushort* W2t = (ushort*)ws;  ws += (size_t)1024 * 1024 * 2;  // 2 MB
    float*  w1  = (float*)ws;   ws += (size_t)R_ * E_ * 4;      // 3.28 MB
    float*  w2  = (float*)ws;                                   // 3.28 MB

    float* out = (float*)d_out;

    prep_kernel<<<3856, 256, 0, stream>>>(
        centre, nbr_idx, graph_w, mr1, mt1, pr1, pt1, mr2, mt2, pr2, pt2,
        node_feats, cw1, cw2, w1, w2, Xb, W1t, W2t);

    fused_gemm_agg_kernel<<<512, 512, 0, stream>>>(Xb, W1t, w1, nbr_idx, hb, nullptr);
    fused_gemm_agg_kernel<<<512, 512, 0, stream>>>(hb, W2t, w2, nbr_idx, nullptr, out);
}